// Round 5
// baseline (7237.901 us; speedup 1.0000x reference)
//
#include <hip/hip_runtime.h>
#include <hip/hip_bf16.h>

using bf16 = __hip_bfloat16;

static __device__ __forceinline__ float ldv(bf16 v) { return __bfloat162float(v); }
static __device__ __forceinline__ float ldv(float v) { return v; }
static __device__ __forceinline__ bf16 f2b(float v) { return __float2bfloat16(v); }
static __device__ __forceinline__ void stv(bf16* p, float v) { *p = __float2bfloat16(v); }
static __device__ __forceinline__ void stv(float* p, float v) { *p = v; }

// ---------------------------------------------------------------------------
// LayerNorm (cols = 1024 fixed). out = (x - mean)*rsqrt(var+1e-5)*gamma [+ add]
// x, gamma, add: fp32 ; out: bf16 workspace
// ---------------------------------------------------------------------------
__global__ __launch_bounds__(256) void ln_kernel(
    const float* __restrict__ x, const float* __restrict__ gamma,
    const float* __restrict__ add, bf16* __restrict__ out) {
  const int row = blockIdx.x;
  const float* xr = x + (size_t)row * 1024;
  float v[4];
  float s = 0.f, ss = 0.f;
#pragma unroll
  for (int i = 0; i < 4; ++i) {
    v[i] = xr[threadIdx.x + 256 * i];
    s += v[i];
    ss += v[i] * v[i];
  }
#pragma unroll
  for (int m = 1; m < 64; m <<= 1) {
    s += __shfl_xor(s, m);
    ss += __shfl_xor(ss, m);
  }
  __shared__ float red[8];
  const int wid = threadIdx.x >> 6;
  if ((threadIdx.x & 63) == 0) { red[wid] = s; red[wid + 4] = ss; }
  __syncthreads();
  s = red[0] + red[1] + red[2] + red[3];
  ss = red[4] + red[5] + red[6] + red[7];
  const float mean = s * (1.f / 1024.f);
  const float var = ss * (1.f / 1024.f) - mean * mean;
  const float rs = rsqrtf(var + 1e-5f);
  bf16* outr = out + (size_t)row * 1024;
#pragma unroll
  for (int i = 0; i < 4; ++i) {
    int c = threadIdx.x + 256 * i;
    float y = (v[i] - mean) * rs * gamma[c];
    if (add) y += add[(size_t)row * 1024 + c];
    outr[c] = f2b(y);
  }
}

// ---------------------------------------------------------------------------
// Tiled GEMM  C[M,N] = Acat[M,K] @ B[K,N], fp32 accumulate.
// A/A2: TA (bf16 ws or fp32 input); B: fp32 weights; C: TC (bf16 ws or fp32 out).
// Acat(m,k) = (A2 && k >= K1) ? A2[m,k-K1] : A[m,k]
// epilogue 1: new_states = sigmoid(beta[n])*(acc + b_gate[n])
//                         + (1-sigmoid(beta[n]))*init_state[m,n]
// tile 64x64, BK=16, 256 threads, 4x4 per thread. M,N %64==0, K %16==0.
// ---------------------------------------------------------------------------
template <typename TA, typename TC>
__global__ __launch_bounds__(256) void gemm_kernel(
    const TA* __restrict__ A, int lda,
    const TA* __restrict__ A2, int lda2, int K1,
    const float* __restrict__ B, int ldb,
    TC* __restrict__ C, int ldc, int K,
    int epilogue,
    const float* __restrict__ b_gate, const float* __restrict__ ema_beta,
    const float* __restrict__ init_state) {
  __shared__ __align__(16) float As[16][68];  // [k][m]
  __shared__ __align__(16) float Bs[16][68];  // [k][n]
  const int bm = blockIdx.y * 64, bn = blockIdx.x * 64;
  const int tx = threadIdx.x & 15, ty = threadIdx.x >> 4;
  const int ar = threadIdx.x >> 2, ac = (threadIdx.x & 3) * 4;
  const int bkr = threadIdx.x >> 4, bc = (threadIdx.x & 15) * 4;
  float acc[4][4] = {};
  for (int kt = 0; kt < K; kt += 16) {
    {
      const int gk0 = kt + ac;
      const TA* ap = (A2 && gk0 >= K1)
                         ? (A2 + (size_t)(bm + ar) * lda2 + (gk0 - K1))
                         : (A + (size_t)(bm + ar) * lda + gk0);
#pragma unroll
      for (int i = 0; i < 4; ++i) As[ac + i][ar] = ldv(ap[i]);
      const float* bp = B + (size_t)(kt + bkr) * ldb + bn + bc;
#pragma unroll
      for (int i = 0; i < 4; ++i) Bs[bkr][bc + i] = bp[i];
    }
    __syncthreads();
#pragma unroll
    for (int kk = 0; kk < 16; ++kk) {
      float4 a4 = *(const float4*)&As[kk][ty * 4];
      float4 b4 = *(const float4*)&Bs[kk][tx * 4];
      float a[4] = {a4.x, a4.y, a4.z, a4.w};
      float b[4] = {b4.x, b4.y, b4.z, b4.w};
#pragma unroll
      for (int i = 0; i < 4; ++i)
#pragma unroll
        for (int j = 0; j < 4; ++j) acc[i][j] += a[i] * b[j];
    }
    __syncthreads();
  }
#pragma unroll
  for (int i = 0; i < 4; ++i) {
    const int m = bm + ty * 4 + i;
#pragma unroll
    for (int j = 0; j < 4; ++j) {
      const int n = bn + tx * 4 + j;
      float v = acc[i][j];
      if (epilogue == 1) {
        float z = v + b_gate[n];
        float d = 1.f / (1.f + __expf(-ema_beta[n]));
        v = d * z + (1.f - d) * init_state[(size_t)m * 1024 + n];
      }
      stv(&C[(size_t)m * ldc + n], v);
    }
  }
}

// ---------------------------------------------------------------------------
// SIMPLE reference-style attention. One block (256 threads) per (qrow, head).
// ---------------------------------------------------------------------------
__global__ __launch_bounds__(256) void attn_simple(
    const bf16* __restrict__ qp, int q_rstride, int q_coff,
    const bf16* __restrict__ kp, int k_rstride, int k_coff,
    const bf16* __restrict__ vp, int v_rstride, int v_coff,
    const float* __restrict__ q_scale, const float* __restrict__ k_scale,
    const float* __restrict__ bias, int causal, int nkeys,
    int use_blocks, int kbase0,
    bf16* __restrict__ op, int o_rstride, int o_coff, int o_hstride) {
  __shared__ float qk[64];
  __shared__ float sc[1024];
  __shared__ float red[4];
  __shared__ float oacc[4][64];
  const int qrow = blockIdx.x;
  const int h = blockIdx.y;
  const int tid = threadIdx.x;
  const int qloc = qrow & 511;
  const int kbase = use_blocks ? ((qrow >> 9) * 512 - 512) : kbase0;

  if (tid < 64) {
    float qv = ldv(qp[(size_t)qrow * q_rstride + q_coff + h * 64 + tid]);
    float ssq = qv * qv;
#pragma unroll
    for (int m = 1; m < 64; m <<= 1) ssq += __shfl_xor(ssq, m);
    const float inv = 8.f / fmaxf(sqrtf(ssq), 1e-12f);
    qk[tid] = qv * inv * q_scale[tid] * k_scale[tid];
  }
  __syncthreads();

  for (int j = tid; j < nkeys; j += 256) {
    const int krow = kbase + j;
    float dot = 0.f, ssk = 0.f;
    if (krow >= 0) {
      const bf16* kr = kp + (size_t)krow * k_rstride + k_coff + h * 64;
#pragma unroll
      for (int d = 0; d < 64; ++d) {
        float kv = ldv(kr[d]);
        dot += qk[d] * kv;
        ssk += kv * kv;
      }
    }
    float s = dot / fmaxf(sqrtf(ssk), 1e-12f);
    if (bias) s += bias[((size_t)h * 512 + qloc) * 1024 + j];
    if (causal && j > qloc + 512) s = -3.0e38f;
    sc[j] = s;
  }
  __syncthreads();

  float mx = -3.0e38f;
  for (int j = tid; j < nkeys; j += 256) mx = fmaxf(mx, sc[j]);
#pragma unroll
  for (int m = 1; m < 64; m <<= 1) mx = fmaxf(mx, __shfl_xor(mx, m));
  if ((tid & 63) == 0) red[tid >> 6] = mx;
  __syncthreads();
  mx = fmaxf(fmaxf(red[0], red[1]), fmaxf(red[2], red[3]));
  __syncthreads();
  float sum = 0.f;
  for (int j = tid; j < nkeys; j += 256) {
    float p = __expf(sc[j] - mx);
    sc[j] = p;
    sum += p;
  }
#pragma unroll
  for (int m = 1; m < 64; m <<= 1) sum += __shfl_xor(sum, m);
  if ((tid & 63) == 0) red[tid >> 6] = sum;
  __syncthreads();
  const float invl = 1.f / (red[0] + red[1] + red[2] + red[3]);

  const int g = tid >> 6, d = tid & 63;
  float od = 0.f;
  for (int j = g; j < nkeys; j += 4) {
    const int krow = kbase + j;
    if (krow >= 0)
      od += sc[j] * ldv(vp[(size_t)krow * v_rstride + v_coff + h * 64 + d]);
  }
  oacc[g][d] = od;
  __syncthreads();
  if (tid < 64) {
    float o = (oacc[0][tid] + oacc[1][tid] + oacc[2][tid] + oacc[3][tid]) * invl;
    op[(size_t)qrow * o_rstride + o_coff + (size_t)h * o_hstride + tid] = f2b(o);
  }
}

// ---------------------------------------------------------------------------
// memories (fp32 out): out[m][h][i][d] = qkv[(3584+i)*3072 + 1024*(m+1) + h*64 + d]
// ---------------------------------------------------------------------------
__global__ __launch_bounds__(256) void memcopy_kernel(const bf16* __restrict__ qkv,
                                                      float* __restrict__ out) {
  const int idx = blockIdx.x * 256 + threadIdx.x;  // 2*16*512*64 = 1048576
  const int d = idx & 63;
  const int i = (idx >> 6) & 511;
  const int h = (idx >> 15) & 15;
  const int mm = idx >> 19;
  out[idx] = ldv(qkv[(size_t)(3584 + i) * 3072 + 1024 * (mm + 1) + h * 64 + d]);
}

// ---------------------------------------------------------------------------
extern "C" void kernel_launch(void* const* d_in, const int* in_sizes, int n_in,
                              void* d_out, int out_size, void* d_ws, size_t ws_size,
                              hipStream_t stream) {
  const float* x = (const float*)d_in[0];
  const float* rel_bias = (const float*)d_in[1];
  const float* gamma = (const float*)d_in[2];
  const float* w_qkv = (const float*)d_in[3];
  const float* q_scale = (const float*)d_in[4];
  const float* k_scale = (const float*)d_in[5];
  const float* w_out = (const float*)d_in[6];
  const float* s_gamma = (const float*)d_in[7];
  const float* w_q2s = (const float*)d_in[8];
  const float* w_qfs = (const float*)d_in[9];
  const float* w_sqkv = (const float*)d_in[10];
  const float* init_state = (const float*)d_in[11];
  const float* state_pos = (const float*)d_in[12];
  const float* w_sout = (const float*)d_in[13];
  const float* ts_qs = (const float*)d_in[14];
  const float* ts_ks = (const float*)d_in[15];
  const float* ss_qs = (const float*)d_in[16];
  const float* ss_ks = (const float*)d_in[17];
  const float* fs_qs = (const float*)d_in[18];
  const float* fs_ks = (const float*)d_in[19];
  const float* w_gate = (const float*)d_in[20];
  const float* b_gate = (const float*)d_in[21];
  const float* ema_beta = (const float*)d_in[22];

  // outputs: FP32 (reference output dtype is float32)
  float* out0 = (float*)d_out;         // [4096,1024]
  float* out_mem = out0 + 4194304;     // [2,16,512,64]
  float* out_ns = out0 + 5242880;      // [512,1024]

  // workspace (bf16 intermediates), 64 MiB total
  bf16* xn = (bf16*)d_ws;          // 4096x1024
  bf16* qkv = xn + 4194304;        // 4096x3072
  bf16* q2s = qkv + 12582912;      // 4096x1024
  bf16* aloc = q2s + 4194304;      // 4096x1024
  bf16* ats = aloc + 4194304;      // 4096x1024
  bf16* st = ats + 4194304;        // 512x1024
  bf16* sqkv = st + 524288;        // 512x3072
  bf16* qfs = sqkv + 1572864;      // 512x1024
  bf16* socat = qfs + 524288;      // 512x2048
  bf16* soproj = socat + 1048576;  // 512x1024

  // 1. layernorms
  ln_kernel<<<4096, 256, 0, stream>>>(x, gamma, nullptr, xn);
  ln_kernel<<<512, 256, 0, stream>>>(init_state, s_gamma, state_pos, st);

  // 2. projections
  gemm_kernel<bf16, bf16><<<dim3(48, 64), 256, 0, stream>>>(
      xn, 1024, nullptr, 0, 0, w_qkv, 3072, qkv, 3072, 1024, 0, nullptr, nullptr, nullptr);
  gemm_kernel<bf16, bf16><<<dim3(16, 64), 256, 0, stream>>>(
      xn, 1024, nullptr, 0, 0, w_q2s, 1024, q2s, 1024, 1024, 0, nullptr, nullptr, nullptr);
  gemm_kernel<float, bf16><<<dim3(48, 8), 256, 0, stream>>>(
      init_state, 1024, nullptr, 0, 0, w_sqkv, 3072, sqkv, 3072, 1024, 0, nullptr, nullptr, nullptr);
  gemm_kernel<bf16, bf16><<<dim3(16, 8), 256, 0, stream>>>(
      st, 1024, nullptr, 0, 0, w_qfs, 1024, qfs, 1024, 1024, 0, nullptr, nullptr, nullptr);

  // 3. attentions (simple two-pass)
  attn_simple<<<dim3(4096, 16), 256, 0, stream>>>(
      qkv, 3072, 0, qkv, 3072, 1024, qkv, 3072, 2048, q_scale, k_scale,
      rel_bias, 1, 1024, 1, 0, aloc, 1024, 0, 64);
  attn_simple<<<dim3(4096, 16), 256, 0, stream>>>(
      q2s, 1024, 0, sqkv, 3072, 1024, sqkv, 3072, 2048, ts_qs, ts_ks,
      nullptr, 0, 512, 0, 0, ats, 1024, 0, 64);
  attn_simple<<<dim3(512, 16), 256, 0, stream>>>(
      sqkv, 3072, 0, sqkv, 3072, 1024, sqkv, 3072, 2048, ss_qs, ss_ks,
      nullptr, 0, 512, 0, 0, socat, 2048, 0, 128);
  attn_simple<<<dim3(512, 16), 256, 0, stream>>>(
      qfs, 1024, 0, qkv, 3072, 1024, qkv, 3072, 2048, fs_qs, fs_ks,
      nullptr, 0, 512, 0, 3584, socat, 2048, 64, 128);

  // 4. memories output (fp32)
  memcopy_kernel<<<4096, 256, 0, stream>>>(qkv, out_mem);

  // 5. out0 = [aloc | ats] @ w_out  (fp32 out)
  gemm_kernel<bf16, float><<<dim3(16, 64), 256, 0, stream>>>(
      aloc, 1024, ats, 1024, 1024, w_out, 1024, out0, 1024, 2048, 0, nullptr, nullptr, nullptr);

  // 6. state out path (new_states fp32 out)
  gemm_kernel<bf16, bf16><<<dim3(16, 8), 256, 0, stream>>>(
      socat, 2048, nullptr, 0, 0, w_sout, 1024, soproj, 1024, 2048, 0, nullptr, nullptr, nullptr);
  gemm_kernel<bf16, float><<<dim3(16, 8), 256, 0, stream>>>(
      soproj, 1024, nullptr, 0, 0, w_gate, 1024, out_ns, 1024, 1024, 1, b_gate, ema_beta,
      init_state);
}

// Round 6
// 3965.131 us; speedup vs baseline: 1.8254x; 1.8254x over previous
//
#include <hip/hip_runtime.h>
#include <hip/hip_bf16.h>

using bf16 = __hip_bfloat16;

static __device__ __forceinline__ float ldv(bf16 v) { return __bfloat162float(v); }
static __device__ __forceinline__ float ldv(float v) { return v; }
static __device__ __forceinline__ bf16 f2b(float v) { return __float2bfloat16(v); }
static __device__ __forceinline__ void stv(bf16* p, float v) { *p = __float2bfloat16(v); }
static __device__ __forceinline__ void stv(float* p, float v) { *p = v; }

// ---------------------------------------------------------------------------
// LayerNorm (cols = 1024 fixed). out = (x - mean)*rsqrt(var+1e-5)*gamma [+ add]
// ---------------------------------------------------------------------------
__global__ __launch_bounds__(256) void ln_kernel(
    const float* __restrict__ x, const float* __restrict__ gamma,
    const float* __restrict__ add, bf16* __restrict__ out) {
  const int row = blockIdx.x;
  const float* xr = x + (size_t)row * 1024;
  float v[4];
  float s = 0.f, ss = 0.f;
#pragma unroll
  for (int i = 0; i < 4; ++i) {
    v[i] = xr[threadIdx.x + 256 * i];
    s += v[i];
    ss += v[i] * v[i];
  }
#pragma unroll
  for (int m = 1; m < 64; m <<= 1) {
    s += __shfl_xor(s, m);
    ss += __shfl_xor(ss, m);
  }
  __shared__ float red[8];
  const int wid = threadIdx.x >> 6;
  if ((threadIdx.x & 63) == 0) { red[wid] = s; red[wid + 4] = ss; }
  __syncthreads();
  s = red[0] + red[1] + red[2] + red[3];
  ss = red[4] + red[5] + red[6] + red[7];
  const float mean = s * (1.f / 1024.f);
  const float var = ss * (1.f / 1024.f) - mean * mean;
  const float rs = rsqrtf(var + 1e-5f);
  bf16* outr = out + (size_t)row * 1024;
#pragma unroll
  for (int i = 0; i < 4; ++i) {
    int c = threadIdx.x + 256 * i;
    float y = (v[i] - mean) * rs * gamma[c];
    if (add) y += add[(size_t)row * 1024 + c];
    outr[c] = f2b(y);
  }
}

// ---------------------------------------------------------------------------
// Tiled GEMM  C[M,N] = Acat[M,K] @ B[K,N], fp32 accumulate.
// ---------------------------------------------------------------------------
template <typename TA, typename TC>
__global__ __launch_bounds__(256) void gemm_kernel(
    const TA* __restrict__ A, int lda,
    const TA* __restrict__ A2, int lda2, int K1,
    const float* __restrict__ B, int ldb,
    TC* __restrict__ C, int ldc, int K,
    int epilogue,
    const float* __restrict__ b_gate, const float* __restrict__ ema_beta,
    const float* __restrict__ init_state) {
  __shared__ __align__(16) float As[16][68];  // [k][m]
  __shared__ __align__(16) float Bs[16][68];  // [k][n]
  const int bm = blockIdx.y * 64, bn = blockIdx.x * 64;
  const int tx = threadIdx.x & 15, ty = threadIdx.x >> 4;
  const int ar = threadIdx.x >> 2, ac = (threadIdx.x & 3) * 4;
  const int bkr = threadIdx.x >> 4, bc = (threadIdx.x & 15) * 4;
  float acc[4][4] = {};
  for (int kt = 0; kt < K; kt += 16) {
    {
      const int gk0 = kt + ac;
      const TA* ap = (A2 && gk0 >= K1)
                         ? (A2 + (size_t)(bm + ar) * lda2 + (gk0 - K1))
                         : (A + (size_t)(bm + ar) * lda + gk0);
#pragma unroll
      for (int i = 0; i < 4; ++i) As[ac + i][ar] = ldv(ap[i]);
      const float* bp = B + (size_t)(kt + bkr) * ldb + bn + bc;
#pragma unroll
      for (int i = 0; i < 4; ++i) Bs[bkr][bc + i] = bp[i];
    }
    __syncthreads();
#pragma unroll
    for (int kk = 0; kk < 16; ++kk) {
      float4 a4 = *(const float4*)&As[kk][ty * 4];
      float4 b4 = *(const float4*)&Bs[kk][tx * 4];
      float a[4] = {a4.x, a4.y, a4.z, a4.w};
      float b[4] = {b4.x, b4.y, b4.z, b4.w};
#pragma unroll
      for (int i = 0; i < 4; ++i)
#pragma unroll
        for (int j = 0; j < 4; ++j) acc[i][j] += a[i] * b[j];
    }
    __syncthreads();
  }
#pragma unroll
  for (int i = 0; i < 4; ++i) {
    const int m = bm + ty * 4 + i;
#pragma unroll
    for (int j = 0; j < 4; ++j) {
      const int n = bn + tx * 4 + j;
      float v = acc[i][j];
      if (epilogue == 1) {
        float z = v + b_gate[n];
        float d = 1.f / (1.f + __expf(-ema_beta[n]));
        v = d * z + (1.f - d) * init_state[(size_t)m * 1024 + n];
      }
      stv(&C[(size_t)m * ldc + n], v);
    }
  }
}

// ---------------------------------------------------------------------------
// Tiled flash attention, D=64, 64-query x 64-key tiles, online softmax.
// q-hat = l2norm(q)*q_scale*8 ; k-hat = l2norm(k)*k_scale ; sim = qhat.khat
// element(ptr,row,h,d) = ptr[row*rstride + coff + h*64 + d]
// key row = kbase0 + blockIdx.z*krows_per_blk + j ; row<0 => zero pad (k=v=0)
// causal: allow j <= qloc + 512 (qloc = position within 512-query block)
// bias (nullable): [h][512][1024], added before mask (local attn only).
// grid: (qtiles, H, nblocks); 256 threads.
// ---------------------------------------------------------------------------
__global__ __launch_bounds__(256) void attn_flash(
    const bf16* __restrict__ qp, int q_rstride, int q_coff,
    const bf16* __restrict__ kp, int k_rstride, int k_coff,
    const bf16* __restrict__ vp, int v_rstride, int v_coff,
    const float* __restrict__ q_scale, const float* __restrict__ k_scale,
    const float* __restrict__ bias, int causal, int nkeys,
    int qrows_per_blk, int kbase0, int krows_per_blk,
    bf16* __restrict__ op, int o_rstride, int o_coff, int o_hstride) {
  __shared__ __align__(16) float qs[64][68];  // [d][qrow]   qhat^T
  __shared__ __align__(16) float ks[64][68];  // [d][krow]   khat^T
  __shared__ __align__(16) float ps[64][68];  // [qrow][krow] P
  __shared__ __align__(16) bf16 vs[64][72];   // [krow][d]
  const int h = blockIdx.y, qt = blockIdx.x, zb = blockIdx.z;
  const int tid = threadIdx.x;
  const int tx = tid & 15, ty = tid >> 4;
  const int sr = tid >> 2, sd = (tid & 3) * 16;  // staging: row, dim-quarter

  // ---- stage q tile (normalize per row over 64 dims, scale, *8) ----
  {
    const int qrow = zb * qrows_per_blk + qt * 64 + sr;
    const bf16* qrp = qp + (size_t)qrow * q_rstride + q_coff + h * 64 + sd;
    float qv[16];
    float ssum = 0.f;
#pragma unroll
    for (int i = 0; i < 16; ++i) { qv[i] = ldv(qrp[i]); ssum += qv[i] * qv[i]; }
    ssum += __shfl_xor(ssum, 1);
    ssum += __shfl_xor(ssum, 2);
    const float inv = 8.f / fmaxf(sqrtf(ssum), 1e-12f);
#pragma unroll
    for (int i = 0; i < 16; ++i) qs[sd + i][sr] = qv[i] * inv * q_scale[sd + i];
  }

  float m_i[4], l_i[4], o[4][4];
#pragma unroll
  for (int i = 0; i < 4; ++i) {
    m_i[i] = -3.0e38f;
    l_i[i] = 0.f;
#pragma unroll
    for (int j = 0; j < 4; ++j) o[i][j] = 0.f;
  }
  const int kbase = kbase0 + zb * krows_per_blk;

  for (int jt = 0; jt < nkeys; jt += 64) {
    __syncthreads();  // protects qs (first iter) and prev-iter ps/vs readers
    // ---- stage k (normalized) and v tiles ----
    {
      const int krow = kbase + jt + sr;
      float kv[16];
      float ssum = 0.f;
      if (krow >= 0) {
        const bf16* krp = kp + (size_t)krow * k_rstride + k_coff + h * 64 + sd;
#pragma unroll
        for (int i = 0; i < 16; ++i) { kv[i] = ldv(krp[i]); ssum += kv[i] * kv[i]; }
      } else {
#pragma unroll
        for (int i = 0; i < 16; ++i) kv[i] = 0.f;
      }
      ssum += __shfl_xor(ssum, 1);
      ssum += __shfl_xor(ssum, 2);
      const float inv = 1.f / fmaxf(sqrtf(ssum), 1e-12f);
#pragma unroll
      for (int i = 0; i < 16; ++i) ks[sd + i][sr] = kv[i] * inv * k_scale[sd + i];
      if (krow >= 0) {
        const bf16* vrp = vp + (size_t)krow * v_rstride + v_coff + h * 64 + sd;
#pragma unroll
        for (int i = 0; i < 16; ++i) vs[sr][sd + i] = vrp[i];
      } else {
        const bf16 z = f2b(0.f);
#pragma unroll
        for (int i = 0; i < 16; ++i) vs[sr][sd + i] = z;
      }
    }
    __syncthreads();

    // ---- scores S = qhat . khat  (4x4 per thread) ----
    float s[4][4] = {};
#pragma unroll
    for (int kk = 0; kk < 64; ++kk) {
      float4 a4 = *(const float4*)&qs[kk][ty * 4];
      float4 b4 = *(const float4*)&ks[kk][tx * 4];
      float a[4] = {a4.x, a4.y, a4.z, a4.w};
      float b[4] = {b4.x, b4.y, b4.z, b4.w};
#pragma unroll
      for (int i = 0; i < 4; ++i)
#pragma unroll
        for (int j = 0; j < 4; ++j) s[i][j] += a[i] * b[j];
    }

    // ---- bias + causal mask ----
#pragma unroll
    for (int i = 0; i < 4; ++i) {
      const int qloc = qt * 64 + ty * 4 + i;
#pragma unroll
      for (int j = 0; j < 4; ++j) {
        const int jg = jt + tx * 4 + j;
        if (bias) s[i][j] += bias[((size_t)h * 512 + qloc) * 1024 + jg];
        if (causal && jg > qloc + 512) s[i][j] = -3.0e38f;
      }
    }

    // ---- online softmax (row groups = 16 threads sharing ty) ----
#pragma unroll
    for (int i = 0; i < 4; ++i) {
      float rmax = fmaxf(fmaxf(s[i][0], s[i][1]), fmaxf(s[i][2], s[i][3]));
#pragma unroll
      for (int mm = 1; mm < 16; mm <<= 1) rmax = fmaxf(rmax, __shfl_xor(rmax, mm));
      const float mn = fmaxf(m_i[i], rmax);
      const float alpha = __expf(m_i[i] - mn);
      float p0 = __expf(s[i][0] - mn), p1 = __expf(s[i][1] - mn);
      float p2 = __expf(s[i][2] - mn), p3 = __expf(s[i][3] - mn);
      float rsum = p0 + p1 + p2 + p3;
#pragma unroll
      for (int mm = 1; mm < 16; mm <<= 1) rsum += __shfl_xor(rsum, mm);
      l_i[i] = l_i[i] * alpha + rsum;
      m_i[i] = mn;
#pragma unroll
      for (int j = 0; j < 4; ++j) o[i][j] *= alpha;
      float4 p4 = make_float4(p0, p1, p2, p3);
      *(float4*)&ps[ty * 4 + i][tx * 4] = p4;
    }
    __syncthreads();

    // ---- O += P @ V ----
#pragma unroll
    for (int kk = 0; kk < 64; ++kk) {
      float a[4];
#pragma unroll
      for (int i = 0; i < 4; ++i) a[i] = ps[ty * 4 + i][kk];
      const bf16* vr = &vs[kk][tx * 4];
      float b[4] = {ldv(vr[0]), ldv(vr[1]), ldv(vr[2]), ldv(vr[3])};
#pragma unroll
      for (int i = 0; i < 4; ++i)
#pragma unroll
        for (int j = 0; j < 4; ++j) o[i][j] += a[i] * b[j];
    }
  }

  // ---- epilogue: O / l ----
#pragma unroll
  for (int i = 0; i < 4; ++i) {
    const int qrow = zb * qrows_per_blk + qt * 64 + ty * 4 + i;
    const float invl = 1.f / l_i[i];
    bf16* orow = op + (size_t)qrow * o_rstride + o_coff + (size_t)h * o_hstride;
#pragma unroll
    for (int j = 0; j < 4; ++j) orow[tx * 4 + j] = f2b(o[i][j] * invl);
  }
}

// ---------------------------------------------------------------------------
// memories (fp32 out): out[m][h][i][d] = qkv[(3584+i)*3072 + 1024*(m+1) + h*64 + d]
// ---------------------------------------------------------------------------
__global__ __launch_bounds__(256) void memcopy_kernel(const bf16* __restrict__ qkv,
                                                      float* __restrict__ out) {
  const int idx = blockIdx.x * 256 + threadIdx.x;  // 2*16*512*64 = 1048576
  const int d = idx & 63;
  const int i = (idx >> 6) & 511;
  const int h = (idx >> 15) & 15;
  const int mm = idx >> 19;
  out[idx] = ldv(qkv[(size_t)(3584 + i) * 3072 + 1024 * (mm + 1) + h * 64 + d]);
}

// ---------------------------------------------------------------------------
extern "C" void kernel_launch(void* const* d_in, const int* in_sizes, int n_in,
                              void* d_out, int out_size, void* d_ws, size_t ws_size,
                              hipStream_t stream) {
  const float* x = (const float*)d_in[0];
  const float* rel_bias = (const float*)d_in[1];
  const float* gamma = (const float*)d_in[2];
  const float* w_qkv = (const float*)d_in[3];
  const float* q_scale = (const float*)d_in[4];
  const float* k_scale = (const float*)d_in[5];
  const float* w_out = (const float*)d_in[6];
  const float* s_gamma = (const float*)d_in[7];
  const float* w_q2s = (const float*)d_in[8];
  const float* w_qfs = (const float*)d_in[9];
  const float* w_sqkv = (const float*)d_in[10];
  const float* init_state = (const float*)d_in[11];
  const float* state_pos = (const float*)d_in[12];
  const float* w_sout = (const float*)d_in[13];
  const float* ts_qs = (const float*)d_in[14];
  const float* ts_ks = (const float*)d_in[15];
  const float* ss_qs = (const float*)d_in[16];
  const float* ss_ks = (const float*)d_in[17];
  const float* fs_qs = (const float*)d_in[18];
  const float* fs_ks = (const float*)d_in[19];
  const float* w_gate = (const float*)d_in[20];
  const float* b_gate = (const float*)d_in[21];
  const float* ema_beta = (const float*)d_in[22];

  // outputs: FP32
  float* out0 = (float*)d_out;         // [4096,1024]
  float* out_mem = out0 + 4194304;     // [2,16,512,64]
  float* out_ns = out0 + 5242880;      // [512,1024]

  // workspace (bf16 intermediates), 64 MiB total
  bf16* xn = (bf16*)d_ws;          // 4096x1024
  bf16* qkv = xn + 4194304;        // 4096x3072
  bf16* q2s = qkv + 12582912;      // 4096x1024
  bf16* aloc = q2s + 4194304;      // 4096x1024
  bf16* ats = aloc + 4194304;      // 4096x1024
  bf16* st = ats + 4194304;        // 512x1024
  bf16* sqkv = st + 524288;        // 512x3072
  bf16* qfs = sqkv + 1572864;      // 512x1024
  bf16* socat = qfs + 524288;      // 512x2048
  bf16* soproj = socat + 1048576;  // 512x1024

  // 1. layernorms
  ln_kernel<<<4096, 256, 0, stream>>>(x, gamma, nullptr, xn);
  ln_kernel<<<512, 256, 0, stream>>>(init_state, s_gamma, state_pos, st);

  // 2. projections
  gemm_kernel<bf16, bf16><<<dim3(48, 64), 256, 0, stream>>>(
      xn, 1024, nullptr, 0, 0, w_qkv, 3072, qkv, 3072, 1024, 0, nullptr, nullptr, nullptr);
  gemm_kernel<bf16, bf16><<<dim3(16, 64), 256, 0, stream>>>(
      xn, 1024, nullptr, 0, 0, w_q2s, 1024, q2s, 1024, 1024, 0, nullptr, nullptr, nullptr);
  gemm_kernel<float, bf16><<<dim3(48, 8), 256, 0, stream>>>(
      init_state, 1024, nullptr, 0, 0, w_sqkv, 3072, sqkv, 3072, 1024, 0, nullptr, nullptr, nullptr);
  gemm_kernel<bf16, bf16><<<dim3(16, 8), 256, 0, stream>>>(
      st, 1024, nullptr, 0, 0, w_qfs, 1024, qfs, 1024, 1024, 0, nullptr, nullptr, nullptr);

  // 3. attentions (tiled flash)
  // local sliding-window: q=qkv[:, :1024], k/v = prev+current block, bias+causal
  attn_flash<<<dim3(8, 16, 8), 256, 0, stream>>>(
      qkv, 3072, 0, qkv, 3072, 1024, qkv, 3072, 2048, q_scale, k_scale,
      rel_bias, 1, 1024, 512, -512, 512, aloc, 1024, 0, 64);
  // to_state: q = q2s (4096 rows), k/v = state k/v (512 rows)
  attn_flash<<<dim3(64, 16, 1), 256, 0, stream>>>(
      q2s, 1024, 0, sqkv, 3072, 1024, sqkv, 3072, 2048, ts_qs, ts_ks,
      nullptr, 0, 512, 4096, 0, 0, ats, 1024, 0, 64);
  // state self-attention -> socat[:, h*128 + 0..63]
  attn_flash<<<dim3(8, 16, 1), 256, 0, stream>>>(
      sqkv, 3072, 0, sqkv, 3072, 1024, sqkv, 3072, 2048, ss_qs, ss_ks,
      nullptr, 0, 512, 512, 0, 0, socat, 2048, 0, 128);
  // from_state: q = qfs, k/v = last block of qkv -> socat[:, h*128+64..]
  attn_flash<<<dim3(8, 16, 1), 256, 0, stream>>>(
      qfs, 1024, 0, qkv, 3072, 1024, qkv, 3072, 2048, fs_qs, fs_ks,
      nullptr, 0, 512, 512, 3584, 0, socat, 2048, 64, 128);

  // 4. memories output (fp32)
  memcopy_kernel<<<4096, 256, 0, stream>>>(qkv, out_mem);

  // 5. out0 = [aloc | ats] @ w_out  (fp32 out)
  gemm_kernel<bf16, float><<<dim3(16, 64), 256, 0, stream>>>(
      aloc, 1024, ats, 1024, 1024, w_out, 1024, out0, 1024, 2048, 0, nullptr, nullptr, nullptr);

  // 6. state out path (new_states fp32 out)
  gemm_kernel<bf16, bf16><<<dim3(16, 8), 256, 0, stream>>>(
      socat, 2048, nullptr, 0, 0, w_sout, 1024, soproj, 1024, 2048, 0, nullptr, nullptr, nullptr);
  gemm_kernel<bf16, float><<<dim3(16, 8), 256, 0, stream>>>(
      soproj, 1024, nullptr, 0, 0, w_gate, 1024, out_ns, 1024, 1024, 1, b_gate, ema_beta,
      init_state);
}

// Round 7
// 1223.727 us; speedup vs baseline: 5.9146x; 3.2402x over previous
//
#include <hip/hip_runtime.h>
#include <hip/hip_bf16.h>

using bf16 = __hip_bfloat16;
using bf16x8 = __attribute__((ext_vector_type(8))) short;
using f32x4 = __attribute__((ext_vector_type(4))) float;

static __device__ __forceinline__ float ldv(bf16 v) { return __bfloat162float(v); }
static __device__ __forceinline__ float ldv(float v) { return v; }
static __device__ __forceinline__ bf16 f2b(float v) { return __float2bfloat16(v); }
static __device__ __forceinline__ void stv(bf16* p, float v) { *p = __float2bfloat16(v); }
static __device__ __forceinline__ void stv(float* p, float v) { *p = v; }

// load 8 elements (bf16 passthrough / fp32 cvt) into LDS as bf16
static __device__ __forceinline__ void load8(const bf16* p, bf16* dst) {
  *(uint4*)dst = *(const uint4*)p;
}
static __device__ __forceinline__ void load8(const float* p, bf16* dst) {
  float4 a = *(const float4*)p, b = *(const float4*)(p + 4);
  dst[0] = f2b(a.x); dst[1] = f2b(a.y); dst[2] = f2b(a.z); dst[3] = f2b(a.w);
  dst[4] = f2b(b.x); dst[5] = f2b(b.y); dst[6] = f2b(b.z); dst[7] = f2b(b.w);
}

// ---------------------------------------------------------------------------
// LayerNorm (cols = 1024 fixed). out = (x - mean)*rsqrt(var+1e-5)*gamma [+ add]
// ---------------------------------------------------------------------------
__global__ __launch_bounds__(256) void ln_kernel(
    const float* __restrict__ x, const float* __restrict__ gamma,
    const float* __restrict__ add, bf16* __restrict__ out) {
  const int row = blockIdx.x;
  const float* xr = x + (size_t)row * 1024;
  float v[4];
  float s = 0.f, ss = 0.f;
#pragma unroll
  for (int i = 0; i < 4; ++i) {
    v[i] = xr[threadIdx.x + 256 * i];
    s += v[i];
    ss += v[i] * v[i];
  }
#pragma unroll
  for (int m = 1; m < 64; m <<= 1) {
    s += __shfl_xor(s, m);
    ss += __shfl_xor(ss, m);
  }
  __shared__ float red[8];
  const int wid = threadIdx.x >> 6;
  if ((threadIdx.x & 63) == 0) { red[wid] = s; red[wid + 4] = ss; }
  __syncthreads();
  s = red[0] + red[1] + red[2] + red[3];
  ss = red[4] + red[5] + red[6] + red[7];
  const float mean = s * (1.f / 1024.f);
  const float var = ss * (1.f / 1024.f) - mean * mean;
  const float rs = rsqrtf(var + 1e-5f);
  bf16* outr = out + (size_t)row * 1024;
#pragma unroll
  for (int i = 0; i < 4; ++i) {
    int c = threadIdx.x + 256 * i;
    float y = (v[i] - mean) * rs * gamma[c];
    if (add) y += add[(size_t)row * 1024 + c];
    outr[c] = f2b(y);
  }
}

// ---------------------------------------------------------------------------
// MFMA GEMM  C[M,N] = Acat[M,K] @ B[K,N]
// A/A2: TA (bf16 ws / fp32 input), row-major. B: fp32 weights [K,N] (cvt->bf16
// during LDS staging, stored [n][k]). 128x128 block tile, 4 waves, each wave
// 64x64 via 4x4 mfma_f32_16x16x32_bf16. M,N %128==0, K %32==0, K1 %8==0.
// epilogue 1: sigmoid-gated EMA (new_states).
// ---------------------------------------------------------------------------
template <typename TA, typename TC>
__global__ __launch_bounds__(256) void mfma_gemm(
    const TA* __restrict__ A, int lda,
    const TA* __restrict__ A2, int lda2, int K1,
    const float* __restrict__ B, int ldb,
    TC* __restrict__ C, int ldc, int K,
    int epilogue,
    const float* __restrict__ b_gate, const float* __restrict__ ema_beta,
    const float* __restrict__ init_state) {
  __shared__ bf16 Asb[128][40];  // [m][k], pad 32->40
  __shared__ bf16 Bsb[128][40];  // [n][k], pad 32->40
  const int bm = blockIdx.y * 128, bn = blockIdx.x * 128;
  const int tid = threadIdx.x;
  const int w = tid >> 6, lane = tid & 63;
  const int wm = (w >> 1) * 64, wn = (w & 1) * 64;
  const int lr = lane & 15, quad = lane >> 4, ko = quad * 8;
  const int sn = tid & 127, skh = (tid >> 7) * 16;  // B staging map

  f32x4 acc[4][4] = {};

  for (int kt = 0; kt < K; kt += 32) {
    // ---- stage A (2 chunks of 8 per thread) ----
#pragma unroll
    for (int c = 0; c < 2; ++c) {
      const int q = tid + 256 * c;
      const int m = q >> 2, kk = (q & 3) * 8;
      const int gk = kt + kk;
      const TA* ap = (A2 && gk >= K1)
                         ? (A2 + (size_t)(bm + m) * lda2 + (gk - K1))
                         : (A + (size_t)(bm + m) * lda + gk);
      load8(ap, &Asb[m][kk]);
    }
    // ---- stage B: thread owns (n, half-k); column reads coalesce over lanes ----
    {
      bf16 tmp[16];
#pragma unroll
      for (int i = 0; i < 16; ++i)
        tmp[i] = f2b(B[(size_t)(kt + skh + i) * ldb + bn + sn]);
      *(uint4*)&Bsb[sn][skh] = *(uint4*)&tmp[0];
      *(uint4*)&Bsb[sn][skh + 8] = *(uint4*)&tmp[8];
    }
    __syncthreads();

    bf16x8 af[4], bfr[4];
#pragma unroll
    for (int i = 0; i < 4; ++i) af[i] = *(const bf16x8*)&Asb[wm + i * 16 + lr][ko];
#pragma unroll
    for (int j = 0; j < 4; ++j) bfr[j] = *(const bf16x8*)&Bsb[wn + j * 16 + lr][ko];
#pragma unroll
    for (int i = 0; i < 4; ++i)
#pragma unroll
      for (int j = 0; j < 4; ++j)
        acc[i][j] = __builtin_amdgcn_mfma_f32_16x16x32_bf16(af[i], bfr[j],
                                                            acc[i][j], 0, 0, 0);
    __syncthreads();
  }

  // ---- epilogue: D[row][col], row=quad*4+r (in-tile), col=lr ----
#pragma unroll
  for (int i = 0; i < 4; ++i) {
#pragma unroll
    for (int j = 0; j < 4; ++j) {
#pragma unroll
      for (int r = 0; r < 4; ++r) {
        const int row = bm + wm + i * 16 + quad * 4 + r;
        const int col = bn + wn + j * 16 + lr;
        float v = acc[i][j][r];
        if (epilogue == 1) {
          float z = v + b_gate[col];
          float d = 1.f / (1.f + __expf(-ema_beta[col]));
          v = d * z + (1.f - d) * init_state[(size_t)row * 1024 + col];
        }
        stv(&C[(size_t)row * ldc + col], v);
      }
    }
  }
}

// ---------------------------------------------------------------------------
// Tiled flash attention, D=64, 64q x 64k tiles, online softmax.
// (unroll-limited inner loops to stay under the 256-VGPR cap — Round 6 spilled)
// ---------------------------------------------------------------------------
__global__ __launch_bounds__(256) void attn_flash(
    const bf16* __restrict__ qp, int q_rstride, int q_coff,
    const bf16* __restrict__ kp, int k_rstride, int k_coff,
    const bf16* __restrict__ vp, int v_rstride, int v_coff,
    const float* __restrict__ q_scale, const float* __restrict__ k_scale,
    const float* __restrict__ bias, int causal, int nkeys,
    int qrows_per_blk, int kbase0, int krows_per_blk,
    bf16* __restrict__ op, int o_rstride, int o_coff, int o_hstride) {
  __shared__ __align__(16) float qs[64][68];  // [d][qrow]   qhat^T
  __shared__ __align__(16) float ks[64][68];  // [d][krow]   khat^T
  __shared__ __align__(16) float ps[64][68];  // [qrow][krow] P
  __shared__ __align__(16) bf16 vs[64][72];   // [krow][d]
  const int h = blockIdx.y, qt = blockIdx.x, zb = blockIdx.z;
  const int tid = threadIdx.x;
  const int tx = tid & 15, ty = tid >> 4;
  const int sr = tid >> 2, sd = (tid & 3) * 16;

  {
    const int qrow = zb * qrows_per_blk + qt * 64 + sr;
    const bf16* qrp = qp + (size_t)qrow * q_rstride + q_coff + h * 64 + sd;
    float qv[16];
    float ssum = 0.f;
#pragma unroll
    for (int i = 0; i < 16; ++i) { qv[i] = ldv(qrp[i]); ssum += qv[i] * qv[i]; }
    ssum += __shfl_xor(ssum, 1);
    ssum += __shfl_xor(ssum, 2);
    const float inv = 8.f / fmaxf(sqrtf(ssum), 1e-12f);
#pragma unroll
    for (int i = 0; i < 16; ++i) qs[sd + i][sr] = qv[i] * inv * q_scale[sd + i];
  }

  float m_i[4], l_i[4], o[4][4];
#pragma unroll
  for (int i = 0; i < 4; ++i) {
    m_i[i] = -3.0e38f;
    l_i[i] = 0.f;
#pragma unroll
    for (int j = 0; j < 4; ++j) o[i][j] = 0.f;
  }
  const int kbase = kbase0 + zb * krows_per_blk;

  for (int jt = 0; jt < nkeys; jt += 64) {
    __syncthreads();
    {
      const int krow = kbase + jt + sr;
      float kv[16];
      float ssum = 0.f;
      if (krow >= 0) {
        const bf16* krp = kp + (size_t)krow * k_rstride + k_coff + h * 64 + sd;
#pragma unroll
        for (int i = 0; i < 16; ++i) { kv[i] = ldv(krp[i]); ssum += kv[i] * kv[i]; }
      } else {
#pragma unroll
        for (int i = 0; i < 16; ++i) kv[i] = 0.f;
      }
      ssum += __shfl_xor(ssum, 1);
      ssum += __shfl_xor(ssum, 2);
      const float inv = 1.f / fmaxf(sqrtf(ssum), 1e-12f);
#pragma unroll
      for (int i = 0; i < 16; ++i) ks[sd + i][sr] = kv[i] * inv * k_scale[sd + i];
      if (krow >= 0) {
        const bf16* vrp = vp + (size_t)krow * v_rstride + v_coff + h * 64 + sd;
#pragma unroll
        for (int i = 0; i < 16; ++i) vs[sr][sd + i] = vrp[i];
      } else {
        const bf16 z = f2b(0.f);
#pragma unroll
        for (int i = 0; i < 16; ++i) vs[sr][sd + i] = z;
      }
    }
    __syncthreads();

    float s[4][4] = {};
#pragma unroll 8
    for (int kk = 0; kk < 64; ++kk) {
      float4 a4 = *(const float4*)&qs[kk][ty * 4];
      float4 b4 = *(const float4*)&ks[kk][tx * 4];
      float a[4] = {a4.x, a4.y, a4.z, a4.w};
      float b[4] = {b4.x, b4.y, b4.z, b4.w};
#pragma unroll
      for (int i = 0; i < 4; ++i)
#pragma unroll
        for (int j = 0; j < 4; ++j) s[i][j] += a[i] * b[j];
    }

#pragma unroll
    for (int i = 0; i < 4; ++i) {
      const int qloc = qt * 64 + ty * 4 + i;
#pragma unroll
      for (int j = 0; j < 4; ++j) {
        const int jg = jt + tx * 4 + j;
        if (bias) s[i][j] += bias[((size_t)h * 512 + qloc) * 1024 + jg];
        if (causal && jg > qloc + 512) s[i][j] = -3.0e38f;
      }
    }

#pragma unroll
    for (int i = 0; i < 4; ++i) {
      float rmax = fmaxf(fmaxf(s[i][0], s[i][1]), fmaxf(s[i][2], s[i][3]));
#pragma unroll
      for (int mm = 1; mm < 16; mm <<= 1) rmax = fmaxf(rmax, __shfl_xor(rmax, mm));
      const float mn = fmaxf(m_i[i], rmax);
      const float alpha = __expf(m_i[i] - mn);
      float p0 = __expf(s[i][0] - mn), p1 = __expf(s[i][1] - mn);
      float p2 = __expf(s[i][2] - mn), p3 = __expf(s[i][3] - mn);
      float rsum = p0 + p1 + p2 + p3;
#pragma unroll
      for (int mm = 1; mm < 16; mm <<= 1) rsum += __shfl_xor(rsum, mm);
      l_i[i] = l_i[i] * alpha + rsum;
      m_i[i] = mn;
#pragma unroll
      for (int j = 0; j < 4; ++j) o[i][j] *= alpha;
      float4 p4 = make_float4(p0, p1, p2, p3);
      *(float4*)&ps[ty * 4 + i][tx * 4] = p4;
    }
    __syncthreads();

#pragma unroll 8
    for (int kk = 0; kk < 64; ++kk) {
      float a[4];
#pragma unroll
      for (int i = 0; i < 4; ++i) a[i] = ps[ty * 4 + i][kk];
      const bf16* vr = &vs[kk][tx * 4];
      float b[4] = {ldv(vr[0]), ldv(vr[1]), ldv(vr[2]), ldv(vr[3])};
#pragma unroll
      for (int i = 0; i < 4; ++i)
#pragma unroll
        for (int j = 0; j < 4; ++j) o[i][j] += a[i] * b[j];
    }
  }

#pragma unroll
  for (int i = 0; i < 4; ++i) {
    const int qrow = zb * qrows_per_blk + qt * 64 + ty * 4 + i;
    const float invl = 1.f / l_i[i];
    bf16* orow = op + (size_t)qrow * o_rstride + o_coff + (size_t)h * o_hstride;
#pragma unroll
    for (int j = 0; j < 4; ++j) orow[tx * 4 + j] = f2b(o[i][j] * invl);
  }
}

// ---------------------------------------------------------------------------
// memories (fp32 out): out[m][h][i][d] = qkv[(3584+i)*3072 + 1024*(m+1) + h*64 + d]
// ---------------------------------------------------------------------------
__global__ __launch_bounds__(256) void memcopy_kernel(const bf16* __restrict__ qkv,
                                                      float* __restrict__ out) {
  const int idx = blockIdx.x * 256 + threadIdx.x;  // 2*16*512*64 = 1048576
  const int d = idx & 63;
  const int i = (idx >> 6) & 511;
  const int h = (idx >> 15) & 15;
  const int mm = idx >> 19;
  out[idx] = ldv(qkv[(size_t)(3584 + i) * 3072 + 1024 * (mm + 1) + h * 64 + d]);
}

// ---------------------------------------------------------------------------
extern "C" void kernel_launch(void* const* d_in, const int* in_sizes, int n_in,
                              void* d_out, int out_size, void* d_ws, size_t ws_size,
                              hipStream_t stream) {
  const float* x = (const float*)d_in[0];
  const float* rel_bias = (const float*)d_in[1];
  const float* gamma = (const float*)d_in[2];
  const float* w_qkv = (const float*)d_in[3];
  const float* q_scale = (const float*)d_in[4];
  const float* k_scale = (const float*)d_in[5];
  const float* w_out = (const float*)d_in[6];
  const float* s_gamma = (const float*)d_in[7];
  const float* w_q2s = (const float*)d_in[8];
  const float* w_qfs = (const float*)d_in[9];
  const float* w_sqkv = (const float*)d_in[10];
  const float* init_state = (const float*)d_in[11];
  const float* state_pos = (const float*)d_in[12];
  const float* w_sout = (const float*)d_in[13];
  const float* ts_qs = (const float*)d_in[14];
  const float* ts_ks = (const float*)d_in[15];
  const float* ss_qs = (const float*)d_in[16];
  const float* ss_ks = (const float*)d_in[17];
  const float* fs_qs = (const float*)d_in[18];
  const float* fs_ks = (const float*)d_in[19];
  const float* w_gate = (const float*)d_in[20];
  const float* b_gate = (const float*)d_in[21];
  const float* ema_beta = (const float*)d_in[22];

  // outputs: FP32
  float* out0 = (float*)d_out;         // [4096,1024]
  float* out_mem = out0 + 4194304;     // [2,16,512,64]
  float* out_ns = out0 + 5242880;      // [512,1024]

  // workspace (bf16 intermediates), 64 MiB total
  bf16* xn = (bf16*)d_ws;          // 4096x1024
  bf16* qkv = xn + 4194304;        // 4096x3072
  bf16* q2s = qkv + 12582912;      // 4096x1024
  bf16* aloc = q2s + 4194304;      // 4096x1024
  bf16* ats = aloc + 4194304;      // 4096x1024
  bf16* st = ats + 4194304;        // 512x1024
  bf16* sqkv = st + 524288;        // 512x3072
  bf16* qfs = sqkv + 1572864;      // 512x1024
  bf16* socat = qfs + 524288;      // 512x2048
  bf16* soproj = socat + 1048576;  // 512x1024

  // 1. layernorms
  ln_kernel<<<4096, 256, 0, stream>>>(x, gamma, nullptr, xn);
  ln_kernel<<<512, 256, 0, stream>>>(init_state, s_gamma, state_pos, st);

  // 2. projections (MFMA)
  mfma_gemm<bf16, bf16><<<dim3(24, 32), 256, 0, stream>>>(
      xn, 1024, nullptr, 0, 0, w_qkv, 3072, qkv, 3072, 1024, 0, nullptr, nullptr, nullptr);
  mfma_gemm<bf16, bf16><<<dim3(8, 32), 256, 0, stream>>>(
      xn, 1024, nullptr, 0, 0, w_q2s, 1024, q2s, 1024, 1024, 0, nullptr, nullptr, nullptr);
  mfma_gemm<float, bf16><<<dim3(24, 4), 256, 0, stream>>>(
      init_state, 1024, nullptr, 0, 0, w_sqkv, 3072, sqkv, 3072, 1024, 0, nullptr, nullptr, nullptr);
  mfma_gemm<bf16, bf16><<<dim3(8, 4), 256, 0, stream>>>(
      st, 1024, nullptr, 0, 0, w_qfs, 1024, qfs, 1024, 1024, 0, nullptr, nullptr, nullptr);

  // 3. attentions (tiled flash)
  attn_flash<<<dim3(8, 16, 8), 256, 0, stream>>>(
      qkv, 3072, 0, qkv, 3072, 1024, qkv, 3072, 2048, q_scale, k_scale,
      rel_bias, 1, 1024, 512, -512, 512, aloc, 1024, 0, 64);
  attn_flash<<<dim3(64, 16, 1), 256, 0, stream>>>(
      q2s, 1024, 0, sqkv, 3072, 1024, sqkv, 3072, 2048, ts_qs, ts_ks,
      nullptr, 0, 512, 4096, 0, 0, ats, 1024, 0, 64);
  attn_flash<<<dim3(8, 16, 1), 256, 0, stream>>>(
      sqkv, 3072, 0, sqkv, 3072, 1024, sqkv, 3072, 2048, ss_qs, ss_ks,
      nullptr, 0, 512, 512, 0, 0, socat, 2048, 0, 128);
  attn_flash<<<dim3(8, 16, 1), 256, 0, stream>>>(
      qfs, 1024, 0, qkv, 3072, 1024, qkv, 3072, 2048, fs_qs, fs_ks,
      nullptr, 0, 512, 512, 3584, 0, socat, 2048, 64, 128);

  // 4. memories output (fp32)
  memcopy_kernel<<<4096, 256, 0, stream>>>(qkv, out_mem);

  // 5. out0 = [aloc | ats] @ w_out  (fp32 out)
  mfma_gemm<bf16, float><<<dim3(8, 32), 256, 0, stream>>>(
      aloc, 1024, ats, 1024, 1024, w_out, 1024, out0, 1024, 2048, 0, nullptr, nullptr, nullptr);

  // 6. state out path (new_states fp32 out)
  mfma_gemm<bf16, bf16><<<dim3(8, 4), 256, 0, stream>>>(
      socat, 2048, nullptr, 0, 0, w_sout, 1024, soproj, 1024, 2048, 0, nullptr, nullptr, nullptr);
  mfma_gemm<bf16, float><<<dim3(8, 4), 256, 0, stream>>>(
      soproj, 1024, nullptr, 0, 0, w_gate, 1024, out_ns, 1024, 1024, 1, b_gate, ema_beta,
      init_state);
}